// Round 2
// baseline (2755.706 us; speedup 1.0000x reference)
//
#include <hip/hip_runtime.h>
#include <hip/hip_bf16.h>
#include <math.h>

// ---------------------------------------------------------------------------
// GPT decision-transformer forward on gfx950.
// DTYPE CONTRACT (round-2 fix): reference declares ALL float tensors as
// float32 -> d_in floats are const float*, d_out is float*. The harness's
// "bf16" label is its error model (floor_eps_k=8), i.e. bf16 compute inside
// the kernel is tolerated. Internal GEMM operands are bf16 (MFMA); residual
// stream X is f32; weights converted f32->bf16 during LDS staging.
// ---------------------------------------------------------------------------

typedef __hip_bfloat16 bf16;
typedef __attribute__((ext_vector_type(4))) short s4v;
typedef __attribute__((ext_vector_type(8))) short s8v;
typedef __attribute__((ext_vector_type(4))) float f4v;

#define DEV static __device__ __forceinline__

constexpr int NBATCH = 2;
constexpr int NK   = 48;
constexpr int NNP  = 25;
constexpr int NC   = 768;
constexpr int NH   = 12;
constexpr int NL   = 6;
constexpr int NTOK = 29;          // rtg + 25 states + action + pnp + intention
constexpr int NT   = NK * NTOK;   // 1392
constexpr int NM   = NBATCH * NT; // 2784 rows in the flattened (B*T, C) stream

DEV float bs2f(short s) {
  unsigned u = ((unsigned)(unsigned short)s) << 16;
  float f; __builtin_memcpy(&f, &u, 4); return f;
}
DEV short f2bs(float f) {
  bf16 h = __float2bfloat16(f);
  short s; __builtin_memcpy(&s, &h, 2); return s;
}

// ---------------------------------------------------------------------------
// Embedding: builds X (B*T, C) f32, exact f32 arithmetic (matches reference).
// One block per (b, timestep).
// ---------------------------------------------------------------------------
__global__ __launch_bounds__(256) void embed_kernel(
    const int* __restrict__ states, const int* __restrict__ actions,
    const float* __restrict__ rtgs, const int* __restrict__ timesteps,
    const float* __restrict__ pnp, const int* __restrict__ intentions,
    const float* __restrict__ pos_emb, const float* __restrict__ gpe,
    const float* __restrict__ state_tab, const float* __restrict__ action_tab,
    const float* __restrict__ retW, const float* __restrict__ retb,
    const float* __restrict__ pnpW, const float* __restrict__ pnpb,
    const float* __restrict__ src_tab, const float* __restrict__ dst_tab,
    const float* __restrict__ intW, const float* __restrict__ intb,
    float* __restrict__ X)
{
  int blk = blockIdx.x;
  int b = blk / NK, ts = blk - b * NK;
  int tid = threadIdx.x;
  int bk = b * NK + ts;

  float rtg = rtgs[bk];
  int tstep = timesteps[bk];
  int act   = actions[bk];
  int i0 = intentions[bk * 2 + 0], i1 = intentions[bk * 2 + 1];

  int sidx[NNP];
  float pv[NNP];
#pragma unroll
  for (int i = 0; i < NNP; i++) sidx[i] = states[b * (NK * NNP) + ts * NNP + i];
#pragma unroll
  for (int i = 0; i < NNP; i++) pv[i] = pnp[bk * NNP + i];

  long base = (long)(b * NT + ts * NTOK) * NC;
  for (int c = tid; c < NC; c += 256) {
    float pos = gpe[(long)tstep * NC + c] + pos_emb[ts * NC + c];
    // token 0: rtg
    X[base + c] = rtg * retW[c] + retb[c] + pos;
    // tokens 1..25: states
#pragma unroll
    for (int i = 0; i < NNP; i++)
      X[base + (1 + i) * NC + c] = state_tab[sidx[i] * NC + c] + pos;
    // token 26: action
    X[base + 26 * NC + c] = action_tab[act * NC + c] + pos;
    // token 27: pnp @ pnp_W + pnp_b
    float ap = pnpb[c];
#pragma unroll
    for (int i = 0; i < NNP; i++) ap += pv[i] * pnpW[i * NC + c];
    X[base + 27 * NC + c] = ap + pos;
    // token 28: concat(src,dst) @ int_W + int_b  (1536-dot)
    float a0 = intb[c], a1 = 0.f, a2 = 0.f, a3 = 0.f;
    for (int j = 0; j < NC; j += 4) {
      a0 += src_tab[i0 * NC + j    ] * intW[(j    ) * NC + c];
      a1 += src_tab[i0 * NC + j + 1] * intW[(j + 1) * NC + c];
      a2 += src_tab[i0 * NC + j + 2] * intW[(j + 2) * NC + c];
      a3 += src_tab[i0 * NC + j + 3] * intW[(j + 3) * NC + c];
    }
    for (int j = 0; j < NC; j += 4) {
      a0 += dst_tab[i1 * NC + j    ] * intW[(NC + j    ) * NC + c];
      a1 += dst_tab[i1 * NC + j + 1] * intW[(NC + j + 1) * NC + c];
      a2 += dst_tab[i1 * NC + j + 2] * intW[(NC + j + 2) * NC + c];
      a3 += dst_tab[i1 * NC + j + 3] * intW[(NC + j + 3) * NC + c];
    }
    X[base + 28 * NC + c] = a0 + a1 + a2 + a3 + pos;
  }
}

// ---------------------------------------------------------------------------
// LayerNorm: X (f32) -> XN (bf16). One block per row. 256 thr, 3 elems each.
// g, b are f32.
// ---------------------------------------------------------------------------
__global__ __launch_bounds__(256) void ln_kernel(
    const float* __restrict__ X, bf16* __restrict__ XN,
    const float* __restrict__ g, const float* __restrict__ bt)
{
  int row = blockIdx.x, tid = threadIdx.x;
  const float* x = X + (long)row * NC;
  float v0 = x[tid], v1 = x[tid + 256], v2 = x[tid + 512];
  float s = v0 + v1 + v2;
#pragma unroll
  for (int o = 32; o > 0; o >>= 1) s += __shfl_down(s, o, 64);
  __shared__ float red[8];
  if ((tid & 63) == 0) red[tid >> 6] = s;
  __syncthreads();
  float mean = (red[0] + red[1] + red[2] + red[3]) * (1.0f / NC);
  float d0 = v0 - mean, d1 = v1 - mean, d2 = v2 - mean;
  float qq = d0 * d0 + d1 * d1 + d2 * d2;
#pragma unroll
  for (int o = 32; o > 0; o >>= 1) qq += __shfl_down(qq, o, 64);
  __syncthreads();
  if ((tid & 63) == 0) red[tid >> 6] = qq;
  __syncthreads();
  float var = (red[0] + red[1] + red[2] + red[3]) * (1.0f / NC);
  float rs = 1.0f / sqrtf(var + 1e-5f);
  bf16* xn = XN + (long)row * NC;
  xn[tid      ] = __float2bfloat16(d0 * rs * g[tid      ] + bt[tid      ]);
  xn[tid + 256] = __float2bfloat16(d1 * rs * g[tid + 256] + bt[tid + 256]);
  xn[tid + 512] = __float2bfloat16(d2 * rs * g[tid + 512] + bt[tid + 512]);
}

// ---------------------------------------------------------------------------
// MFMA bf16 GEMM: out = act(A @ W + bias) [+ residual f32 accumulate]
// A (M,K) bf16 rm (internal buffer), W (K,Ngroup) f32 rm (input weights,
// converted to bf16 during staging). 128x128 tile, BK=32, 4 waves (2x2),
// each wave 4x4 subtiles of 16x16x32. Triple-pointer W for fused QKV.
// flags: bit0 = exact GELU, bit1 = f32 residual accumulate into `resid`.
// ---------------------------------------------------------------------------
constexpr int BSTR = 40;  // LDS row stride (shorts): 32 frag + 8 pad

__global__ __launch_bounds__(256) void gemm_kernel(
    const bf16* __restrict__ A,
    const float* __restrict__ W0, const float* __restrict__ W1, const float* __restrict__ W2,
    const float* __restrict__ bias0, const float* __restrict__ bias1, const float* __restrict__ bias2,
    bf16* __restrict__ o0, bf16* __restrict__ o1, bf16* __restrict__ o2,
    float* __restrict__ resid,
    int M, int Ngroup, int K, int flags)
{
  __shared__ short As[128 * BSTR];  // As[m][k]
  __shared__ short Bs[128 * BSTR];  // Bs[n][k]  (transposed W tile)

  int tid = threadIdx.x;
  int wave = tid >> 6, lane = tid & 63, quad = lane >> 4, l16 = lane & 15;
  int m0 = blockIdx.y * 128;
  int ngl = blockIdx.x * 128;
  int which = ngl / Ngroup;
  int n0 = ngl - which * Ngroup;
  const float* W = which == 0 ? W0 : (which == 1 ? W1 : W2);
  const float* bias = which == 0 ? bias0 : (which == 1 ? bias1 : bias2);
  bf16* outb = which == 0 ? o0 : (which == 1 ? o1 : o2);
  const short* Ag = (const short*)A;

  int wm = (wave >> 1) * 64, wn = (wave & 1) * 64;

  f4v zero4 = {0.f, 0.f, 0.f, 0.f};
  f4v acc[4][4];
#pragma unroll
  for (int i = 0; i < 4; i++)
#pragma unroll
    for (int j = 0; j < 4; j++) acc[i][j] = zero4;

  int am = tid >> 1, ak = (tid & 1) * 16;   // A stage: row am, k-offset ak..ak+15
  int bk = tid >> 3, bn = (tid & 7) * 16;   // B stage: k-row bk, n-offset bn..bn+15
  bool a_ok = (m0 + am) < M;

  for (int kt = 0; kt < K; kt += 32) {
    s8v av0 = {0,0,0,0,0,0,0,0}, av1 = av0;
    if (a_ok) {
      const s8v* p = (const s8v*)(Ag + (long)(m0 + am) * K + kt + ak);
      av0 = p[0]; av1 = p[1];
    }
    const float4* q = (const float4*)(W + (long)(kt + bk) * Ngroup + n0 + bn);
    float4 w0 = q[0], w1 = q[1], w2 = q[2], w3 = q[3];

    __syncthreads();   // prior iteration's fragment reads complete
    short* apt = &As[am * BSTR + ak];
    *(s4v*)(apt    ) = av0.lo; *(s4v*)(apt + 4) = av0.hi;
    *(s4v*)(apt + 8) = av1.lo; *(s4v*)(apt + 12) = av1.hi;
    short* bpt = &Bs[bn * BSTR + bk];
    bpt[ 0 * BSTR] = f2bs(w0.x); bpt[ 1 * BSTR] = f2bs(w0.y);
    bpt[ 2 * BSTR] = f2bs(w0.z); bpt[ 3 * BSTR] = f2bs(w0.w);
    bpt[ 4 * BSTR] = f2bs(w1.x); bpt[ 5 * BSTR] = f2bs(w1.y);
    bpt[ 6 * BSTR] = f2bs(w1.z); bpt[ 7 * BSTR] = f2bs(w1.w);
    bpt[ 8 * BSTR] = f2bs(w2.x); bpt[ 9 * BSTR] = f2bs(w2.y);
    bpt[10 * BSTR] = f2bs(w2.z); bpt[11 * BSTR] = f2bs(w2.w);
    bpt[12 * BSTR] = f2bs(w3.x); bpt[13 * BSTR] = f2bs(w3.y);
    bpt[14 * BSTR] = f2bs(w3.z); bpt[15 * BSTR] = f2bs(w3.w);
    __syncthreads();

    s8v af[4], bf8[4];
#pragma unroll
    for (int i = 0; i < 4; i++) {
      const short* p = &As[(wm + i * 16 + l16) * BSTR + quad * 8];
      af[i].lo = *(const s4v*)p; af[i].hi = *(const s4v*)(p + 4);
    }
#pragma unroll
    for (int j = 0; j < 4; j++) {
      const short* p = &Bs[(wn + j * 16 + l16) * BSTR + quad * 8];
      bf8[j].lo = *(const s4v*)p; bf8[j].hi = *(const s4v*)(p + 4);
    }
#pragma unroll
    for (int i = 0; i < 4; i++)
#pragma unroll
      for (int j = 0; j < 4; j++)
        acc[i][j] = __builtin_amdgcn_mfma_f32_16x16x32_bf16(af[i], bf8[j], acc[i][j], 0, 0, 0);
  }

  // epilogue: C/D layout col=lane&15, row=quad*4+reg
#pragma unroll
  for (int i = 0; i < 4; i++) {
    int rbase = m0 + wm + i * 16 + quad * 4;
#pragma unroll
    for (int j = 0; j < 4; j++) {
      int col = n0 + wn + j * 16 + l16;
      float bv = bias[col];
#pragma unroll
      for (int r = 0; r < 4; r++) {
        int row = rbase + r;
        if (row < M) {
          float v = acc[i][j][r] + bv;
          if (flags & 1) v = 0.5f * v * (1.0f + erff(v * 0.70710678118654752f));
          if (flags & 2) resid[(long)row * Ngroup + col] += v;
          else outb[(long)row * Ngroup + col] = __float2bfloat16(v);
        }
      }
    }
  }
}

// ---------------------------------------------------------------------------
// Flash-style causal attention, MFMA. Block = (q-tile 64, head, batch).
// Q,K,V bf16 (B*T, C); head slice cols h*64..+64. Online softmax (f32 stats),
// P round-trips LDS as bf16 for the PV MFMA.
// ---------------------------------------------------------------------------
constexpr int ASTR = 72;  // 64 + 8 pad shorts

__global__ __launch_bounds__(256) void attn_kernel(
    const bf16* __restrict__ Qg, const bf16* __restrict__ Kg,
    const bf16* __restrict__ Vg, bf16* __restrict__ Yg)
{
  int qt = blockIdx.x, h = blockIdx.y, b = blockIdx.z;
  int q0 = qt * 64;
  int tid = threadIdx.x, wave = tid >> 6, lane = tid & 63, quad = lane >> 4, l16 = lane & 15;

  __shared__ short Qs[64 * ASTR];
  __shared__ short Ks[64 * ASTR];
  __shared__ short Vt[64 * ASTR];   // V transposed: Vt[d][c]
  __shared__ short Ps[64 * ASTR];   // exp(S-m) as bf16
  __shared__ float S[64 * 65];
  __shared__ float mrow[64], lrow[64], arow[64];
  __shared__ float red[256];

  if (tid < 64) { mrow[tid] = -1e30f; lrow[tid] = 0.f; }

  int r = tid >> 2, c16 = (tid & 3) * 16;
  const short* qsrc = (const short*)Qg;
  const short* ksrc = (const short*)Kg;
  const short* vsrc = (const short*)Vg;
  s8v zz = {0,0,0,0,0,0,0,0};

  s8v qv0 = zz, qv1 = zz;
  if (q0 + r < NT) {
    const s8v* p = (const s8v*)(qsrc + (long)(b * NT + q0 + r) * NC + h * 64 + c16);
    qv0 = p[0]; qv1 = p[1];
  }
  {
    short* qp = &Qs[r * ASTR + c16];
    *(s4v*)(qp    ) = qv0.lo; *(s4v*)(qp + 4) = qv0.hi;
    *(s4v*)(qp + 8) = qv1.lo; *(s4v*)(qp + 12) = qv1.hi;
  }

  f4v zero4 = {0.f, 0.f, 0.f, 0.f};
  f4v Of[4];
#pragma unroll
  for (int j = 0; j < 4; j++) Of[j] = zero4;

  int kend = q0 + 63; if (kend > NT - 1) kend = NT - 1;
  for (int k0 = 0; k0 <= kend; k0 += 64) {
    s8v kv0 = zz, kv1 = zz, vv0 = zz, vv1 = zz;
    if (k0 + r < NT) {
      const s8v* pk = (const s8v*)(ksrc + (long)(b * NT + k0 + r) * NC + h * 64 + c16);
      kv0 = pk[0]; kv1 = pk[1];
      const s8v* pvv = (const s8v*)(vsrc + (long)(b * NT + k0 + r) * NC + h * 64 + c16);
      vv0 = pvv[0]; vv1 = pvv[1];
    }
    __syncthreads();  // sync1: previous iter's PV reads (Ps,Vt) + S-mfma reads (Ks) done
    {
      short* kp = &Ks[r * ASTR + c16];
      *(s4v*)(kp    ) = kv0.lo; *(s4v*)(kp + 4) = kv0.hi;
      *(s4v*)(kp + 8) = kv1.lo; *(s4v*)(kp + 12) = kv1.hi;
      short* vt = &Vt[c16 * ASTR + r];
      vt[ 0 * ASTR] = vv0.s0; vt[ 1 * ASTR] = vv0.s1; vt[ 2 * ASTR] = vv0.s2; vt[ 3 * ASTR] = vv0.s3;
      vt[ 4 * ASTR] = vv0.s4; vt[ 5 * ASTR] = vv0.s5; vt[ 6 * ASTR] = vv0.s6; vt[ 7 * ASTR] = vv0.s7;
      vt[ 8 * ASTR] = vv1.s0; vt[ 9 * ASTR] = vv1.s1; vt[10 * ASTR] = vv1.s2; vt[11 * ASTR] = vv1.s3;
      vt[12 * ASTR] = vv1.s4; vt[13 * ASTR] = vv1.s5; vt[14 * ASTR] = vv1.s6; vt[15 * ASTR] = vv1.s7;
    }
    __syncthreads();  // sync2

    // S = Q @ K^T  (wave -> q-rows wave*16..+16, 4 col-subtiles, 2 k-steps over d)
    f4v sa[4];
#pragma unroll
    for (int j = 0; j < 4; j++) sa[j] = zero4;
#pragma unroll
    for (int ks = 0; ks < 2; ks++) {
      const short* pa = &Qs[(wave * 16 + l16) * ASTR + ks * 32 + quad * 8];
      s8v aq; aq.lo = *(const s4v*)pa; aq.hi = *(const s4v*)(pa + 4);
#pragma unroll
      for (int j = 0; j < 4; j++) {
        const short* pb = &Ks[(j * 16 + l16) * ASTR + ks * 32 + quad * 8];
        s8v bk8; bk8.lo = *(const s4v*)pb; bk8.hi = *(const s4v*)(pb + 4);
        sa[j] = __builtin_amdgcn_mfma_f32_16x16x32_bf16(aq, bk8, sa[j], 0, 0, 0);
      }
    }
    // scale + causal mask -> S (f32, stride 65)
#pragma unroll
    for (int j = 0; j < 4; j++) {
#pragma unroll
      for (int rg = 0; rg < 4; rg++) {
        int rloc = wave * 16 + quad * 4 + rg;
        int cloc = j * 16 + l16;
        int gq = q0 + rloc, gk = k0 + cloc;
        float sv = (gk <= gq && gq < NT) ? sa[j][rg] * 0.125f : -1e30f;
        S[rloc * 65 + cloc] = sv;
      }
    }
    __syncthreads();  // sync3

    // row max (4 partials per row)
    float mx = -1e30f;
#pragma unroll
    for (int c = 0; c < 16; c++) mx = fmaxf(mx, S[r * 65 + c16 + c]);
    red[r * 4 + (tid & 3)] = mx;
    __syncthreads();  // sync4
    if (tid < 64) {
      float tm = fmaxf(fmaxf(red[tid * 4], red[tid * 4 + 1]), fmaxf(red[tid * 4 + 2], red[tid * 4 + 3]));
      float mn = fmaxf(mrow[tid], tm);
      arow[tid] = __expf(mrow[tid] - mn);
      mrow[tid] = mn;
    }
    __syncthreads();  // sync5

    // P = exp(S - m) -> Ps (bf16); row-sum partials
    float mr = mrow[r];
    float psum = 0.f;
#pragma unroll
    for (int c = 0; c < 16; c++) {
      float e = __expf(S[r * 65 + c16 + c] - mr);
      psum += e;
      Ps[r * ASTR + c16 + c] = f2bs(e);
    }
    red[r * 4 + (tid & 3)] = psum;
    __syncthreads();  // sync6
    if (tid < 64)
      lrow[tid] = lrow[tid] * arow[tid] + red[tid * 4] + red[tid * 4 + 1] + red[tid * 4 + 2] + red[tid * 4 + 3];
    // rescale O by alpha (per C/D row)
#pragma unroll
    for (int j = 0; j < 4; j++)
#pragma unroll
      for (int rg = 0; rg < 4; rg++)
        Of[j][rg] *= arow[wave * 16 + quad * 4 + rg];
    __syncthreads();  // sync7: Ps fully written

    // O += P @ V  (A=Ps rows, B=Vt rows: Vt[d][c])
#pragma unroll
    for (int ks = 0; ks < 2; ks++) {
      const short* pa = &Ps[(wave * 16 + l16) * ASTR + ks * 32 + quad * 8];
      s8v ap8; ap8.lo = *(const s4v*)pa; ap8.hi = *(const s4v*)(pa + 4);
#pragma unroll
      for (int j = 0; j < 4; j++) {
        const short* pb = &Vt[(j * 16 + l16) * ASTR + ks * 32 + quad * 8];
        s8v vp8; vp8.lo = *(const s4v*)pb; vp8.hi = *(const s4v*)(pb + 4);
        Of[j] = __builtin_amdgcn_mfma_f32_16x16x32_bf16(ap8, vp8, Of[j], 0, 0, 0);
      }
    }
  }
  __syncthreads();
#pragma unroll
  for (int j = 0; j < 4; j++) {
#pragma unroll
    for (int rg = 0; rg < 4; rg++) {
      int rloc = wave * 16 + quad * 4 + rg;
      int gq = q0 + rloc;
      if (gq < NT) {
        float ov = Of[j][rg] / lrow[rloc];
        Yg[(long)(b * NT + gq) * NC + h * 64 + j * 16 + l16] = __float2bfloat16(ov);
      }
    }
  }
}

// ---------------------------------------------------------------------------
// Heads: XN bf16 (final-LN output), weights/bias f32, out f32.
// ---------------------------------------------------------------------------
__global__ __launch_bounds__(256) void head_logits_kernel(
    const bf16* __restrict__ XN, const float* __restrict__ Whs,
    const float* __restrict__ bhs, float* __restrict__ out)
{
  int idx = blockIdx.x * 256 + threadIdx.x;
  if (idx >= NM * 10) return;
  int row = idx / 10, n = idx - row * 10;
  const short* x = (const short*)XN + (long)row * NC;
  float a0 = bhs[n], a1 = 0.f, a2 = 0.f, a3 = 0.f;
  for (int k = 0; k < NC; k += 4) {
    a0 += bs2f(x[k    ]) * Whs[(k    ) * 10 + n];
    a1 += bs2f(x[k + 1]) * Whs[(k + 1) * 10 + n];
    a2 += bs2f(x[k + 2]) * Whs[(k + 2) * 10 + n];
    a3 += bs2f(x[k + 3]) * Whs[(k + 3) * 10 + n];
  }
  out[idx] = a0 + a1 + a2 + a3;
}

__global__ __launch_bounds__(128) void head_small_kernel(
    const bf16* __restrict__ XN,
    const float* __restrict__ Wha, const float* __restrict__ bha,
    const float* __restrict__ Whr, const float* __restrict__ bhr,
    const float* __restrict__ Whi, const float* __restrict__ bhi,
    float* __restrict__ outA, float* __restrict__ outR,
    float* __restrict__ outS, float* __restrict__ outD)
{
  int blk = blockIdx.x;                    // b*NK + ts
  int b = blk / NK, ts = blk - b * NK;
  int tid = threadIdx.x;
  if (tid >= 93) return;
  const short* xs = (const short*)XN;
  if (tid < 40) {
    long row = (long)(b * NT + ts * NTOK + 26) * NC;
    float a0 = bha[tid], a1 = 0.f, a2 = 0.f, a3 = 0.f;
    for (int k = 0; k < NC; k += 4) {
      a0 += bs2f(xs[row + k    ]) * Wha[(k    ) * 40 + tid];
      a1 += bs2f(xs[row + k + 1]) * Wha[(k + 1) * 40 + tid];
      a2 += bs2f(xs[row + k + 2]) * Wha[(k + 2) * 40 + tid];
      a3 += bs2f(xs[row + k + 3]) * Wha[(k + 3) * 40 + tid];
    }
    outA[blk * 40 + tid] = a0 + a1 + a2 + a3;
  } else if (tid == 40) {
    long row = (long)(b * NT + ts * NTOK) * NC;
    float a0 = bhr[0], a1 = 0.f, a2 = 0.f, a3 = 0.f;
    for (int k = 0; k < NC; k += 4) {
      a0 += bs2f(xs[row + k    ]) * Whr[k    ];
      a1 += bs2f(xs[row + k + 1]) * Whr[k + 1];
      a2 += bs2f(xs[row + k + 2]) * Whr[k + 2];
      a3 += bs2f(xs[row + k + 3]) * Whr[k + 3];
    }
    outR[blk] = a0 + a1 + a2 + a3;
  } else {
    int n = tid - 41;                      // 0..51
    long row = (long)(b * NT + ts * NTOK + 28) * NC;
    float a0 = bhi[n], a1 = 0.f, a2 = 0.f, a3 = 0.f;
    for (int k = 0; k < NC; k += 4) {
      a0 += bs2f(xs[row + k    ]) * Whi[(k    ) * 52 + n];
      a1 += bs2f(xs[row + k + 1]) * Whi[(k + 1) * 52 + n];
      a2 += bs2f(xs[row + k + 2]) * Whi[(k + 2) * 52 + n];
      a3 += bs2f(xs[row + k + 3]) * Whi[(k + 3) * 52 + n];
    }
    if (n < 26) outS[blk * 26 + n] = a0 + a1 + a2 + a3;
    else        outD[blk * 26 + (n - 26)] = a0 + a1 + a2 + a3;
  }
}

// ---------------------------------------------------------------------------
extern "C" void kernel_launch(void* const* d_in, const int* in_sizes, int n_in,
                              void* d_out, int out_size, void* d_ws, size_t ws_size,
                              hipStream_t stream)
{
  (void)in_sizes; (void)n_in; (void)out_size; (void)ws_size;

  const int*   states     = (const int*)  d_in[0];
  const int*   actions    = (const int*)  d_in[1];
  const float* rtgs       = (const float*)d_in[2];
  const int*   timesteps  = (const int*)  d_in[3];
  const float* pnp        = (const float*)d_in[4];
  const int*   intentions = (const int*)  d_in[5];
  const float* pos_emb    = (const float*)d_in[6];
  const float* gpe        = (const float*)d_in[7];
  const float* state_tab  = (const float*)d_in[8];
  const float* action_tab = (const float*)d_in[9];
  const float* retW  = (const float*)d_in[10];
  const float* retb  = (const float*)d_in[11];
  const float* pnpW  = (const float*)d_in[12];
  const float* pnpb  = (const float*)d_in[13];
  const float* src_tab = (const float*)d_in[14];
  const float* dst_tab = (const float*)d_in[15];
  const float* intW  = (const float*)d_in[16];
  const float* intb  = (const float*)d_in[17];
  const float* ln1g  = (const float*)d_in[18];
  const float* ln1b  = (const float*)d_in[19];
  const float* ln2g  = (const float*)d_in[20];
  const float* ln2b  = (const float*)d_in[21];
  const float* Wq = (const float*)d_in[22];
  const float* bq = (const float*)d_in[23];
  const float* Wk = (const float*)d_in[24];
  const float* bk = (const float*)d_in[25];
  const float* Wv = (const float*)d_in[26];
  const float* bv = (const float*)d_in[27];
  const float* Wo = (const float*)d_in[28];
  const float* bo = (const float*)d_in[29];
  const float* Wm1 = (const float*)d_in[30];
  const float* bm1 = (const float*)d_in[31];
  const float* Wm2 = (const float*)d_in[32];
  const float* bm2 = (const float*)d_in[33];
  const float* lnfg = (const float*)d_in[34];
  const float* lnfb = (const float*)d_in[35];
  const float* Whs = (const float*)d_in[36];
  const float* bhs = (const float*)d_in[37];
  const float* Wha = (const float*)d_in[38];
  const float* bha = (const float*)d_in[39];
  const float* Whr = (const float*)d_in[40];
  const float* bhr = (const float*)d_in[41];
  const float* Whi = (const float*)d_in[42];
  const float* bhi = (const float*)d_in[43];

  // workspace layout (29,933,568 B total). H1 aliases Q/K/V/Y (liveness is
  // disjoint: H1 live FC1->FC2, QKVY live QKV->O-proj, stream-serial).
  char* wsb = (char*)d_ws;
  float* X  = (float*)(wsb);               // (2784,768) f32 = 8,552,448 B
  bf16* XN  = (bf16*)(wsb +  8552448);     // (2784,768) bf16 = 4,276,224 B
  bf16* Qb  = (bf16*)(wsb + 12828672);     // 4 x 4,276,224 B region
  bf16* Kb  = Qb + (long)NM * NC;
  bf16* Vb  = Kb + (long)NM * NC;
  bf16* Yb  = Vb + (long)NM * NC;
  bf16* H1  = Qb;                          // (2784,3072) bf16, aliases QKVY

  float* out0 = (float*)d_out;       // logits       (2,1392,10)
  float* out1 = out0 + 27840;        // logit_action (2,48,40)
  float* out2 = out1 + 3840;         // logit_rtg    (2,48)
  float* out3 = out2 + 96;           // li_src       (2,48,26)
  float* out4 = out3 + 2496;         // li_dst       (2,48,26)

  embed_kernel<<<NBATCH * NK, 256, 0, stream>>>(
      states, actions, rtgs, timesteps, pnp, intentions,
      pos_emb, gpe, state_tab, action_tab, retW, retb, pnpW, pnpb,
      src_tab, dst_tab, intW, intb, X);

  dim3 gQKV(18, 22), gC(6, 22), gFC1(24, 22);
  for (int l = 0; l < NL; l++) {
    const long wofs = (long)l * NC * NC;
    const long mofs1 = (long)l * NC * 4 * NC;
    ln_kernel<<<NM, 256, 0, stream>>>(X, XN, ln1g + l * NC, ln1b + l * NC);
    gemm_kernel<<<gQKV, 256, 0, stream>>>(XN, Wq + wofs, Wk + wofs, Wv + wofs,
        bq + l * NC, bk + l * NC, bv + l * NC, Qb, Kb, Vb, nullptr, NM, NC, NC, 0);
    attn_kernel<<<dim3(22, NH, NBATCH), 256, 0, stream>>>(Qb, Kb, Vb, Yb);
    gemm_kernel<<<gC, 256, 0, stream>>>(Yb, Wo + wofs, Wo + wofs, Wo + wofs,
        bo + l * NC, bo + l * NC, bo + l * NC, nullptr, nullptr, nullptr, X, NM, NC, NC, 2);
    ln_kernel<<<NM, 256, 0, stream>>>(X, XN, ln2g + l * NC, ln2b + l * NC);
    gemm_kernel<<<gFC1, 256, 0, stream>>>(XN, Wm1 + mofs1, Wm1 + mofs1, Wm1 + mofs1,
        bm1 + l * 4 * NC, bm1 + l * 4 * NC, bm1 + l * 4 * NC, H1, H1, H1, nullptr,
        NM, 4 * NC, NC, 1);
    gemm_kernel<<<gC, 256, 0, stream>>>(H1, Wm2 + mofs1, Wm2 + mofs1, Wm2 + mofs1,
        bm2 + l * NC, bm2 + l * NC, bm2 + l * NC, nullptr, nullptr, nullptr, X,
        NM, NC, 4 * NC, 2);
  }
  ln_kernel<<<NM, 256, 0, stream>>>(X, XN, lnfg, lnfb);
  head_logits_kernel<<<(NM * 10 + 255) / 256, 256, 0, stream>>>(XN, Whs, bhs, out0);
  head_small_kernel<<<NBATCH * NK, 128, 0, stream>>>(XN, Wha, bha, Whr, bhr, Whi, bhi,
      out1, out2, out3, out4);
}

// Round 3
// 1807.398 us; speedup vs baseline: 1.5247x; 1.5247x over previous
//
#include <hip/hip_runtime.h>
#include <hip/hip_bf16.h>
#include <math.h>

// ---------------------------------------------------------------------------
// GPT decision-transformer forward on gfx950 — round 3.
// Inputs f32/int32, output f32. Internals: residual X f32, GEMM operands bf16.
// GEMM = m97 structure: per-layer weight transpose+convert to bf16 (N,K), then
// global_load_lds(16B) staging for both operands, ds_read_b128 fragments,
// 16x16x32 bf16 MFMA. QKV fused (N=2304). N=768 GEMMs use 128x64 tiles.
// ---------------------------------------------------------------------------

typedef __hip_bfloat16 bf16;
typedef __attribute__((ext_vector_type(4))) short s4v;
typedef __attribute__((ext_vector_type(8))) short s8v;
typedef __attribute__((ext_vector_type(4))) float f4v;
typedef unsigned int u32;

#define DEV static __device__ __forceinline__

constexpr int NBATCH = 2;
constexpr int NK   = 48;
constexpr int NNP  = 25;
constexpr int NC   = 768;
constexpr int NH   = 12;
constexpr int NL   = 6;
constexpr int NTOK = 29;
constexpr int NT   = NK * NTOK;    // 1392
constexpr int NM   = NBATCH * NT;  // 2784
constexpr int MPAD = 2816;         // 22 * 128

DEV float bs2f(short s) {
  unsigned u = ((unsigned)(unsigned short)s) << 16;
  float f; __builtin_memcpy(&f, &u, 4); return f;
}
DEV short f2bs(float f) {
  bf16 h = __float2bfloat16(f);
  short s; __builtin_memcpy(&s, &h, 2); return s;
}

// async global->LDS copy, 16 B per lane; lds dest = wave-uniform base + lane*16
DEV void async16(const short* g, short* l) {
  __builtin_amdgcn_global_load_lds(
      (const __attribute__((address_space(1))) u32*)g,
      (__attribute__((address_space(3))) u32*)l, 16, 0, 0);
}

// ---------------------------------------------------------------------------
// Weight transpose+convert: f32 (R,C) -> bf16 (C,R). Generic (for intW).
// grid (C/32, R/32), 256 thr.
// ---------------------------------------------------------------------------
__global__ __launch_bounds__(256) void transpose_kernel(
    const float* __restrict__ src, bf16* __restrict__ dst, int R, int C)
{
  int c0 = blockIdx.x * 32, r0 = blockIdx.y * 32;
  __shared__ float tl[32][33];
  int rr = threadIdx.x >> 5, cc = threadIdx.x & 31;
#pragma unroll
  for (int p = 0; p < 4; p++)
    tl[rr + p * 8][cc] = src[(long)(r0 + rr + p * 8) * C + c0 + cc];
  __syncthreads();
#pragma unroll
  for (int p = 0; p < 4; p++)
    dst[(long)(c0 + rr + p * 8) * R + r0 + cc] = __float2bfloat16(tl[cc][rr + p * 8]);
}

// Combined per-layer transpose: Wq/Wk/Wv -> WqkvT (2304,768); Wo -> WoT;
// Wm1 (768,3072) -> Wm1T (3072,768); Wm2 (3072,768) -> Wm2T (768,3072).
// grid 6912 blocks.
__global__ __launch_bounds__(256) void transpose_layer_kernel(
    const float* __restrict__ Wq, const float* __restrict__ Wk,
    const float* __restrict__ Wv, const float* __restrict__ Wo,
    const float* __restrict__ Wm1, const float* __restrict__ Wm2,
    bf16* __restrict__ WqkvT, bf16* __restrict__ WoT,
    bf16* __restrict__ Wm1T, bf16* __restrict__ Wm2T)
{
  int t = blockIdx.x;
  const float* src; bf16* dst; int R, C, tile;
  if (t < 1728) {                       // q,k,v
    int m = t / 576; tile = t - m * 576;
    src = m == 0 ? Wq : (m == 1 ? Wk : Wv);
    dst = WqkvT + (long)m * 768 * 768; R = 768; C = 768;
  } else if (t < 2304) { src = Wo;  dst = WoT;  tile = t - 1728; R = 768;  C = 768;  }
  else if (t < 4608)   { src = Wm1; dst = Wm1T; tile = t - 2304; R = 768;  C = 3072; }
  else                 { src = Wm2; dst = Wm2T; tile = t - 4608; R = 3072; C = 768;  }
  int ct = C / 32;
  int tr = tile / ct, tc = tile - tr * ct;
  int r0 = tr * 32, c0 = tc * 32;
  __shared__ float tl[32][33];
  int rr = threadIdx.x >> 5, cc = threadIdx.x & 31;
#pragma unroll
  for (int p = 0; p < 4; p++)
    tl[rr + p * 8][cc] = src[(long)(r0 + rr + p * 8) * C + c0 + cc];
  __syncthreads();
#pragma unroll
  for (int p = 0; p < 4; p++)
    dst[(long)(c0 + rr + p * 8) * R + r0 + cc] = __float2bfloat16(tl[cc][rr + p * 8]);
}

// ---------------------------------------------------------------------------
// gather ie_in (96,1536) bf16 = [src_tab[i0] | dst_tab[i1]]
// ---------------------------------------------------------------------------
__global__ __launch_bounds__(256) void gather_ie_kernel(
    const int* __restrict__ intentions, const float* __restrict__ src_tab,
    const float* __restrict__ dst_tab, bf16* __restrict__ ie_in)
{
  int idx = blockIdx.x * 256 + threadIdx.x;
  if (idx >= 96 * 1536) return;
  int row = idx / 1536, col = idx - row * 1536;
  float v;
  if (col < 768) v = src_tab[intentions[row * 2 + 0] * 768 + col];
  else           v = dst_tab[intentions[row * 2 + 1] * 768 + col - 768];
  ie_in[idx] = __float2bfloat16(v);
}

// ---------------------------------------------------------------------------
// Embedding: X (B*T, C) f32. grid (96, 3); thread owns one channel c.
// ie token comes precomputed (ieb bf16, 96x768).
// ---------------------------------------------------------------------------
__global__ __launch_bounds__(256) void embed_kernel(
    const int* __restrict__ states, const int* __restrict__ actions,
    const float* __restrict__ rtgs, const int* __restrict__ timesteps,
    const float* __restrict__ pnp,
    const float* __restrict__ pos_emb, const float* __restrict__ gpe,
    const float* __restrict__ state_tab, const float* __restrict__ action_tab,
    const float* __restrict__ retW, const float* __restrict__ retb,
    const float* __restrict__ pnpW, const float* __restrict__ pnpb,
    const bf16* __restrict__ ieb, float* __restrict__ X)
{
  int bk = blockIdx.x;                  // b*NK + ts
  int b = bk / NK, ts = bk - b * NK;
  int c = blockIdx.y * 256 + threadIdx.x;

  float rtg = rtgs[bk];
  int tstep = timesteps[bk];
  int act   = actions[bk];

  long base = (long)(b * NT + ts * NTOK) * NC;
  float pos = gpe[(long)tstep * NC + c] + pos_emb[ts * NC + c];

  X[base + c] = rtg * retW[c] + retb[c] + pos;
  const int* sp = states + bk * NNP;
#pragma unroll
  for (int i = 0; i < NNP; i++)
    X[base + (1 + i) * NC + c] = state_tab[sp[i] * NC + c] + pos;
  X[base + 26 * NC + c] = action_tab[act * NC + c] + pos;
  float ap = pnpb[c];
  const float* pv = pnp + bk * NNP;
#pragma unroll
  for (int i = 0; i < NNP; i++) ap += pv[i] * pnpW[i * NC + c];
  X[base + 27 * NC + c] = ap + pos;
  X[base + 28 * NC + c] = __bfloat162float(ieb[bk * NC + c]) + pos;
}

// ---------------------------------------------------------------------------
// LayerNorm: X (f32) -> XN (bf16). One block per row.
// ---------------------------------------------------------------------------
__global__ __launch_bounds__(256) void ln_kernel(
    const float* __restrict__ X, bf16* __restrict__ XN,
    const float* __restrict__ g, const float* __restrict__ bt)
{
  int row = blockIdx.x, tid = threadIdx.x;
  const float* x = X + (long)row * NC;
  float v0 = x[tid], v1 = x[tid + 256], v2 = x[tid + 512];
  float s = v0 + v1 + v2;
#pragma unroll
  for (int o = 32; o > 0; o >>= 1) s += __shfl_down(s, o, 64);
  __shared__ float red[8];
  if ((tid & 63) == 0) red[tid >> 6] = s;
  __syncthreads();
  float mean = (red[0] + red[1] + red[2] + red[3]) * (1.0f / NC);
  float d0 = v0 - mean, d1 = v1 - mean, d2 = v2 - mean;
  float qq = d0 * d0 + d1 * d1 + d2 * d2;
#pragma unroll
  for (int o = 32; o > 0; o >>= 1) qq += __shfl_down(qq, o, 64);
  __syncthreads();
  if ((tid & 63) == 0) red[tid >> 6] = qq;
  __syncthreads();
  float var = (red[0] + red[1] + red[2] + red[3]) * (1.0f / NC);
  float rs = 1.0f / sqrtf(var + 1e-5f);
  bf16* xn = XN + (long)row * NC;
  xn[tid      ] = __float2bfloat16(d0 * rs * g[tid      ] + bt[tid      ]);
  xn[tid + 256] = __float2bfloat16(d1 * rs * g[tid + 256] + bt[tid + 256]);
  xn[tid + 512] = __float2bfloat16(d2 * rs * g[tid + 512] + bt[tid + 512]);
}

// ---------------------------------------------------------------------------
// MFMA GEMM, m97 structure. A (MPAD,K) bf16 rm; WT (N,K) bf16 rm.
// BM=128, BN in {128,64}, BK=32. global_load_lds 16B staging, unpadded LDS
// rows (64 B), b128 fragment reads. flags: bit0 GELU, bit1 resid += (f32).
// Bias split for fused QKV via Nsplit (which = col / Nsplit -> b0/b1/b2).
// ---------------------------------------------------------------------------
template<int BN>
__global__ __launch_bounds__(256) void gemm_kernel(
    const bf16* __restrict__ A, const bf16* __restrict__ WT,
    const float* __restrict__ b0, const float* __restrict__ b1,
    const float* __restrict__ b2, int Nsplit,
    bf16* __restrict__ outb, float* __restrict__ resid,
    int M, int N, int K, int flags)
{
  constexpr int IM = (BN == 128) ? 4 : 2;
  __shared__ __align__(1024) short As[128 * 32];
  __shared__ __align__(1024) short Bs[BN * 32];

  int tid = threadIdx.x, wave = tid >> 6, lane = tid & 63;
  int quad = lane >> 4, l16 = lane & 15;
  int m0 = blockIdx.y * 128, n0 = blockIdx.x * BN;
  int wm = (BN == 128) ? (wave >> 1) * 64 : wave * 32;
  int wn = (BN == 128) ? (wave & 1) * 64 : 0;
  int lr = lane >> 2, lc = (lane & 3) * 8;

  const short* Ag = (const short*)A + (long)m0 * K + lc;
  const short* Bg = (const short*)WT + (long)n0 * K + lc;

  const short* agp0 = Ag + (long)((wave * 2 + 0) * 16 + lr) * K;
  const short* agp1 = Ag + (long)((wave * 2 + 1) * 16 + lr) * K;
  short* al0 = &As[(wave * 2 + 0) * 16 * 32];
  short* al1 = &As[(wave * 2 + 1) * 16 * 32];
  const short* bgp0; const short* bgp1 = nullptr;
  short* bl0; short* bl1 = nullptr;
  if (BN == 128) {
    bgp0 = Bg + (long)((wave * 2 + 0) * 16 + lr) * K;
    bgp1 = Bg + (long)((wave * 2 + 1) * 16 + lr) * K;
    bl0 = &Bs[(wave * 2 + 0) * 16 * 32];
    bl1 = &Bs[(wave * 2 + 1) * 16 * 32];
  } else {
    bgp0 = Bg + (long)(wave * 16 + lr) * K;
    bl0 = &Bs[wave * 16 * 32];
  }

  f4v zero4 = {0.f, 0.f, 0.f, 0.f};
  f4v acc[IM][4];
#pragma unroll
  for (int i = 0; i < IM; i++)
#pragma unroll
    for (int j = 0; j < 4; j++) acc[i][j] = zero4;

  for (int kt = 0; kt < K; kt += 32) {
    __syncthreads();                    // all waves done reading prev tile
    async16(agp0 + kt, al0);
    async16(agp1 + kt, al1);
    async16(bgp0 + kt, bl0);
    if (BN == 128) async16(bgp1 + kt, bl1);
    __syncthreads();                    // vmcnt(0) drain -> tile ready

    s8v af[IM], bf8[4];
#pragma unroll
    for (int i = 0; i < IM; i++) {
      const short* p = &As[(wm + i * 16 + l16) * 32 + quad * 8];
      af[i].lo = *(const s4v*)p; af[i].hi = *(const s4v*)(p + 4);
    }
#pragma unroll
    for (int j = 0; j < 4; j++) {
      const short* p = &Bs[(wn + j * 16 + l16) * 32 + quad * 8];
      bf8[j].lo = *(const s4v*)p; bf8[j].hi = *(const s4v*)(p + 4);
    }
#pragma unroll
    for (int i = 0; i < IM; i++)
#pragma unroll
      for (int j = 0; j < 4; j++)
        acc[i][j] = __builtin_amdgcn_mfma_f32_16x16x32_bf16(af[i], bf8[j], acc[i][j], 0, 0, 0);
  }

  // epilogue: C/D layout col=lane&15, row=quad*4+reg
#pragma unroll
  for (int i = 0; i < IM; i++) {
    int rbase = m0 + wm + i * 16 + quad * 4;
#pragma unroll
    for (int j = 0; j < 4; j++) {
      int bc = n0 + wn + j * 16;
      int wsel = bc / Nsplit;
      const float* bp = wsel == 0 ? b0 : (wsel == 1 ? b1 : b2);
      float bv = bp[bc - wsel * Nsplit + l16];
      int col = bc + l16;
#pragma unroll
      for (int r = 0; r < 4; r++) {
        int row = rbase + r;
        if (row < M) {
          float v = acc[i][j][r] + bv;
          if (flags & 1) v = 0.5f * v * (1.0f + erff(v * 0.70710678118654752f));
          if (flags & 2) resid[(long)row * N + col] += v;
          else outb[(long)row * N + col] = __float2bfloat16(v);
        }
      }
    }
  }
}

// ---------------------------------------------------------------------------
// Flash-style causal attention. QKV packed (MPAD,2304): Q|K|V col offsets
// 0/768/1536, head slice h*64. Output Yb (MPAD,768) bf16.
// ---------------------------------------------------------------------------
constexpr int ASTR = 72;

__global__ __launch_bounds__(256) void attn_kernel(
    const bf16* __restrict__ QKV, bf16* __restrict__ Yg)
{
  int qt = blockIdx.x, h = blockIdx.y, b = blockIdx.z;
  int q0 = qt * 64;
  int tid = threadIdx.x, wave = tid >> 6, lane = tid & 63, quad = lane >> 4, l16 = lane & 15;

  __shared__ short Qs[64 * ASTR];
  __shared__ short Ks[64 * ASTR];
  __shared__ short Vt[64 * ASTR];
  __shared__ short Ps[64 * ASTR];
  __shared__ float S[64 * 65];
  __shared__ float mrow[64], lrow[64], arow[64];
  __shared__ float red[256];

  if (tid < 64) { mrow[tid] = -1e30f; lrow[tid] = 0.f; }

  int r = tid >> 2, c16 = (tid & 3) * 16;
  const short* src = (const short*)QKV;
  s8v zz = {0,0,0,0,0,0,0,0};

  s8v qv0 = zz, qv1 = zz;
  if (q0 + r < NT) {
    const s8v* p = (const s8v*)(src + (long)(b * NT + q0 + r) * 2304 + h * 64 + c16);
    qv0 = p[0]; qv1 = p[1];
  }
  {
    short* qp = &Qs[r * ASTR + c16];
    *(s4v*)(qp    ) = qv0.lo; *(s4v*)(qp + 4) = qv0.hi;
    *(s4v*)(qp + 8) = qv1.lo; *(s4v*)(qp + 12) = qv1.hi;
  }

  f4v zero4 = {0.f, 0.f, 0.f, 0.f};
  f4v Of[4];
#pragma unroll
  for (int j = 0; j < 4; j++) Of[j] = zero4;

  int kend = q0 + 63; if (kend > NT - 1) kend = NT - 1;
  for (int k0 = 0; k0 <= kend; k0 += 64) {
    s8v kv0 = zz, kv1 = zz, vv0 = zz, vv1 = zz;
    if (k0 + r < NT) {
      const s8v* pk = (const s8v*)(src + (long)(b * NT + k0 + r) * 2304 + 768 + h * 64 + c16);
      kv0 = pk[0]; kv1 = pk[1];
      const s8v* pvv = (const s8v*)(src + (long)(b * NT + k0 + r) * 2304 + 1536 + h * 64 + c16);
      vv0 = pvv[0]; vv1 = pvv[1];
    }
    __syncthreads();
    {
      short* kp = &Ks[r * ASTR + c16];
      *(s4v*)(kp    ) = kv0.lo; *(s4v*)(kp + 4) = kv0.hi;
      *(s4v*)(kp + 8) = kv1.lo; *(s4v*)(kp + 12) = kv1.hi;
      short* vt = &Vt[c16 * ASTR + r];
      vt[ 0 * ASTR] = vv0.s0; vt[ 1 * ASTR] = vv0.s1; vt[ 2 * ASTR] = vv0.s2; vt[ 3 * ASTR] = vv0.s3;
      vt[ 4 * ASTR] = vv0.s4; vt[ 5 * ASTR] = vv0.s5; vt[ 6 * ASTR] = vv0.s6; vt[ 7 * ASTR] = vv0.s7;
      vt[ 8 * ASTR] = vv1.s0; vt[ 9 * ASTR] = vv1.s1; vt[10 * ASTR] = vv1.s2; vt[11 * ASTR] = vv1.s3;
      vt[12 * ASTR] = vv1.s4; vt[13 * ASTR] = vv1.s5; vt[14 * ASTR] = vv1.s6; vt[15 * ASTR] = vv1.s7;
    }
    __syncthreads();

    f4v sa[4];
#pragma unroll
    for (int j = 0; j < 4; j++) sa[j] = zero4;
#pragma unroll
    for (int ks = 0; ks < 2; ks++) {
      const short* pa = &Qs[(wave * 16 + l16) * ASTR + ks * 32 + quad * 8];
      s8v aq; aq.lo = *(const s4v*)pa; aq.hi = *(const s4v*)(pa + 4);
#pragma unroll
      for (int j = 0; j < 4; j++) {
        const short* pb = &Ks[(j * 16 + l16) * ASTR + ks * 32 + quad * 8];
        s8v bk8; bk8.lo = *(const s4v*)pb; bk8.hi = *(const s4v*)(pb + 4);
        sa[j] = __builtin_amdgcn_mfma_f32_16x16x32_bf16(aq, bk8, sa[j], 0, 0, 0);
      }
    }
#pragma unroll
    for (int j = 0; j < 4; j++) {
#pragma unroll
      for (int rg = 0; rg < 4; rg++) {
        int rloc = wave * 16 + quad * 4 + rg;
        int cloc = j * 16 + l16;
        int gq = q0 + rloc, gk = k0 + cloc;
        float sv = (gk <= gq && gq < NT) ? sa[j][rg] * 0.125f : -1e30f;
        S[rloc * 65 + cloc] = sv;
      }
    }
    __syncthreads();

    float mx = -1e30f;
#pragma unroll
    for (int c = 0; c < 16; c++) mx = fmaxf(mx, S[r * 65 + c16 + c]);
    red[r * 4 + (tid & 3)] = mx;
    __syncthreads();
    if (tid < 64) {
      float tm = fmaxf(fmaxf(red[tid * 4], red[tid * 4 + 1]), fmaxf(red[tid * 4 + 2], red[tid * 4 + 3]));
      float mn = fmaxf(mrow[tid], tm);
      arow[tid] = __expf(mrow[tid] - mn);
      mrow[tid] = mn;
    }
    __syncthreads();

    float mr = mrow[r];
    float psum = 0.f;
#pragma unroll
    for (int c = 0; c < 16; c++) {
      float e = __expf(S[r * 65 + c16 + c] - mr);
      psum += e;
      Ps[r * ASTR + c16 + c] = f2bs(e);
    }
    red[r * 4 + (tid & 3)] = psum;
    __syncthreads();
    if (tid < 64)
      lrow[tid] = lrow[tid] * arow[tid] + red[tid * 4] + red[tid * 4 + 1] + red[tid * 4 + 2] + red[tid * 4 + 3];
#pragma unroll
    for (int j = 0; j < 4; j++)
#pragma unroll
      for (int rg = 0; rg < 4; rg++)
        Of[j][rg] *= arow[wave * 16 + quad * 4 + rg];
    __syncthreads();

#pragma unroll
    for (int ks = 0; ks < 2; ks++) {
      const short* pa = &Ps[(wave * 16 + l16) * ASTR + ks * 32 + quad * 8];
      s8v ap8; ap8.lo = *(const s4v*)pa; ap8.hi = *(const s4v*)(pa + 4);
#pragma unroll
      for (int j = 0; j < 4; j++) {
        const short* pb = &Vt[(j * 16 + l16) * ASTR + ks * 32 + quad * 8];
        s8v vp8; vp8.lo = *(const s4v*)pb; vp8.hi = *(const s4v*)(pb + 4);
        Of[j] = __builtin_amdgcn_mfma_f32_16x16x32_bf16(ap8, vp8, Of[j], 0, 0, 0);
      }
    }
  }
  __syncthreads();
#pragma unroll
  for (int j = 0; j < 4; j++) {
#pragma unroll
    for (int rg = 0; rg < 4; rg++) {
      int rloc = wave * 16 + quad * 4 + rg;
      int gq = q0 + rloc;
      if (gq < NT) {
        float ov = Of[j][rg] / lrow[rloc];
        Yg[(long)(b * NT + gq) * NC + h * 64 + j * 16 + l16] = __float2bfloat16(ov);
      }
    }
  }
}

// ---------------------------------------------------------------------------
// Heads
// ---------------------------------------------------------------------------
__global__ __launch_bounds__(256) void head_logits_kernel(
    const bf16* __restrict__ XN, const float* __restrict__ Whs,
    const float* __restrict__ bhs, float* __restrict__ out)
{
  int idx = blockIdx.x * 256 + threadIdx.x;
  if (idx >= NM * 10) return;
  int row = idx / 10, n = idx - row * 10;
  const short* x = (const short*)XN + (long)row * NC;
  float a0 = bhs[n], a1 = 0.f, a2 = 0.f, a3 = 0.f;
  for (int k = 0; k < NC; k += 4) {
    a0 += bs2f(x[k    ]) * Whs[(k    ) * 10 + n];
    a1 += bs2f(x[k + 1]) * Whs[(k + 1) * 10 + n];
    a2 += bs2f(x[k + 2]) * Whs[(k + 2) * 10 + n];
    a3 += bs2f(x[k + 3]) * Whs[(k + 3) * 10 + n];
  }
  out[idx] = a0 + a1 + a2 + a3;
}

__global__ __launch_bounds__(128) void head_small_kernel(
    const bf16* __restrict__ XN,
    const float* __restrict__ Wha, const float* __restrict__ bha,
    const float* __restrict__ Whr, const float* __restrict__ bhr,
    const float* __restrict__ Whi, const float* __restrict__ bhi,
    float* __restrict__ outA, float* __restrict__ outR,
    float* __restrict__ outS, float* __restrict__ outD)
{
  int blk = blockIdx.x;
  int b = blk / NK, ts = blk - b * NK;
  int tid = threadIdx.x;
  if (tid >= 93) return;
  const short* xs = (const short*)XN;
  if (tid < 40) {
    long row = (long)(b * NT + ts * NTOK + 26) * NC;
    float a0 = bha[tid], a1 = 0.f, a2 = 0.f, a3 = 0.f;
    for (int k = 0; k < NC; k += 4) {
      a0 += bs2f(xs[row + k    ]) * Wha[(k    ) * 40 + tid];
      a1 += bs2f(xs[row + k + 1]) * Wha[(k + 1) * 40 + tid];
      a2 += bs2f(xs[row + k + 2]) * Wha[(k + 2) * 40 + tid];
      a3 += bs2f(xs[row + k + 3]) * Wha[(k + 3) * 40 + tid];
    }
    outA[blk * 40 + tid] = a0 + a1 + a2 + a3;
  } else if (tid == 40) {
    long row = (long)(b * NT + ts * NTOK) * NC;
    float a0 = bhr[0], a1 = 0.f, a2 = 0.f, a3 = 0.f;
    for (int k = 0; k < NC; k += 4) {
      a0 += bs2f(xs[row + k    ]) * Whr[k    ];
      a1 += bs2f(xs[row + k + 1]) * Whr[k + 1];
      a2 += bs2f(xs[row + k + 2]) * Whr[k + 2];
      a3 += bs2f(xs[row + k + 3]) * Whr[k + 3];
    }
    outR[blk] = a0 + a1 + a2 + a3;
  } else {
    int n = tid - 41;
    long row = (long)(b * NT + ts * NTOK + 28) * NC;
    float a0 = bhi[n], a1 = 0.f, a2 = 0.f, a3 = 0.f;
    for (int k = 0; k < NC; k += 4) {
      a0 += bs2f(xs[row + k    ]) * Whi[(k    ) * 52 + n];
      a1 += bs2f(xs[row + k + 1]) * Whi[(k + 1) * 52 + n];
      a2 += bs2f(xs[row + k + 2]) * Whi[(k + 2) * 52 + n];
      a3 += bs2f(xs[row + k + 3]) * Whi[(k + 3) * 52 + n];
    }
    if (n < 26) outS[blk * 26 + n] = a0 + a1 + a2 + a3;
    else        outD[blk * 26 + (n - 26)] = a0 + a1 + a2 + a3;
  }
}

// ---------------------------------------------------------------------------
extern "C" void kernel_launch(void* const* d_in, const int* in_sizes, int n_in,
                              void* d_out, int out_size, void* d_ws, size_t ws_size,
                              hipStream_t stream)
{
  (void)in_sizes; (void)n_in; (void)out_size; (void)ws_size;

  const int*   states     = (const int*)  d_in[0];
  const int*   actions    = (const int*)  d_in[1];
  const float* rtgs       = (const float*)d_in[2];
  const int*   timesteps  = (const int*)  d_in[3];
  const float* pnp        = (const float*)d_in[4];
  const int*   intentions = (const int*)  d_in[5];
  const float* pos_emb    = (const float*)d_in[6];
  const float* gpe        = (const float*)d_in[7];
  const float* state_tab  = (const float*)d_in[8];
  const float* action_tab = (const float*)d_in[9];
  const float* retW  = (const float*)d_in[10];
  const float* retb  = (const float*)d_in[11];
  const float* pnpW  = (const float*)d_in[12];
  const float* pnpb  = (const float*)d_in[13];
  const float* src_tab = (const float*)d_in[14];
  const float* dst_tab = (const float*)d_in[15];
  const float* intW  = (const float*)d_in[16];
  const float* intb  = (const float*)d_in[17];
  const float* ln1g  = (const float*)d_in[18];
  const float* ln1b  = (const float*)d_in[19];
  const float* ln2g  = (const float*)d_in[20];
  const float* ln2b  = (const float*)d_in[21];
  const float* Wq = (const float*)d_in[22];
  const float* bq = (const float*)d_in[23];
  const float* Wk = (const float*)d_in[24];
  const float* bk = (const float*)d_in[25];
  const float* Wv = (const float*)d_in[26];
  const float* bv = (const float*)d_in[27];
  const float* Wo = (const float*)d_in[28];
  const float* bo = (const float*)d_in[29];
  const float* Wm1 = (const float*)d_in[30];
  const float* bm1 = (const float*)d_in[31];
  const float* Wm2 = (const float*)d_in[32];
  const float* bm2 = (const float*)d_in[33];
  const float* lnfg = (const float*)d_in[34];
  const float* lnfb = (const float*)d_in[35];
  const float* Whs = (const float*)d_in[36];
  const float* bhs = (const float*)d_in[37];
  const float* Wha = (const float*)d_in[38];
  const float* bha = (const float*)d_in[39];
  const float* Whr = (const float*)d_in[40];
  const float* bhr = (const float*)d_in[41];
  const float* Whi = (const float*)d_in[42];
  const float* bhi = (const float*)d_in[43];

  // ws layout (44,433,408 B total):
  //  X     f32 (MPAD,768)         @ 0          8,650,752
  //  XN    bf16 (MPAD,768)        @ 8,650,752  4,325,376
  //  QKVb  bf16 (MPAD,2304)       @ 12,976,128 12,976,128   } H1 (MPAD,3072)
  //  Yb    bf16 (MPAD,768)        @ 25,952,256  4,325,376   } aliases both
  //  WT    per-layer weights      @ 30,277,632 14,155,776
  //        (startup: intWT 2,359,296 | ie_in 393,216 | ieb 196,608)
  char* wsb = (char*)d_ws;
  float* X   = (float*)(wsb);
  bf16* XN   = (bf16*)(wsb + 8650752);
  bf16* QKVb = (bf16*)(wsb + 12976128);
  bf16* Yb   = (bf16*)(wsb + 25952256);
  bf16* H1   = QKVb;                       // aliases QKVb|Yb (17,301,504 B)
  bf16* WqkvT = (bf16*)(wsb + 30277632);               // (2304,768)
  bf16* WoT   = WqkvT + (long)2304 * 768;              // (768,768)
  bf16* Wm1T  = WoT + (long)768 * 768;                 // (3072,768)
  bf16* Wm2T  = Wm1T + (long)3072 * 768;               // (768,3072)
  bf16* intWT = (bf16*)(wsb + 30277632);               // (768,1536) startup
  bf16* ie_in = intWT + (long)768 * 1536;              // (128,1536)
  bf16* ieb   = ie_in + (long)128 * 1536;              // (128,768)

  float* out0 = (float*)d_out;
  float* out1 = out0 + 27840;
  float* out2 = out1 + 3840;
  float* out3 = out2 + 96;
  float* out4 = out3 + 2496;

  // --- embeddings ---
  transpose_kernel<<<dim3(768 / 32, 1536 / 32), 256, 0, stream>>>(intW, intWT, 1536, 768);
  gather_ie_kernel<<<(96 * 1536 + 255) / 256, 256, 0, stream>>>(intentions, src_tab, dst_tab, ie_in);
  gemm_kernel<64><<<dim3(12, 1), 256, 0, stream>>>(ie_in, intWT, intb, intb, intb, 768,
      ieb, nullptr, 96, 768, 1536, 0);
  embed_kernel<<<dim3(96, 3), 256, 0, stream>>>(
      states, actions, rtgs, timesteps, pnp, pos_emb, gpe, state_tab, action_tab,
      retW, retb, pnpW, pnpb, ieb, X);

  // --- transformer stack ---
  for (int l = 0; l < NL; l++) {
    const long wofs = (long)l * NC * NC;
    const long mofs = (long)l * NC * 4 * NC;
    transpose_layer_kernel<<<6912, 256, 0, stream>>>(
        Wq + wofs, Wk + wofs, Wv + wofs, Wo + wofs, Wm1 + mofs, Wm2 + mofs,
        WqkvT, WoT, Wm1T, Wm2T);
    ln_kernel<<<NM, 256, 0, stream>>>(X, XN, ln1g + l * NC, ln1b + l * NC);
    gemm_kernel<128><<<dim3(18, 22), 256, 0, stream>>>(XN, WqkvT,
        bq + l * NC, bk + l * NC, bv + l * NC, 768, QKVb, nullptr, NM, 2304, NC, 0);
    attn_kernel<<<dim3(22, NH, NBATCH), 256, 0, stream>>>(QKVb, Yb);
    gemm_kernel<64><<<dim3(12, 22), 256, 0, stream>>>(Yb, WoT,
        bo + l * NC, bo + l * NC, bo + l * NC, 768, nullptr, X, NM, 768, NC, 2);
    ln_kernel<<<NM, 256, 0, stream>>>(X, XN, ln2g + l * NC, ln2b + l * NC);
    gemm_kernel<128><<<dim3(24, 22), 256, 0, stream>>>(XN, Wm1T,
        bm1 + l * 4 * NC, bm1 + l * 4 * NC, bm1 + l * 4 * NC, 4 * NC, H1, nullptr,
        NM, 3072, NC, 1);
    gemm_kernel<64><<<dim3(12, 22), 256, 0, stream>>>(H1, Wm2T,
        bm2 + l * NC, bm2 + l * NC, bm2 + l * NC, 768, nullptr, X, NM, 768, 4 * NC, 2);
  }
  ln_kernel<<<NM, 256, 0, stream>>>(X, XN, lnfg, lnfb);
  head_logits_kernel<<<(NM * 10 + 255) / 256, 256, 0, stream>>>(XN, Whs, bhs, out0);
  head_small_kernel<<<NBATCH * NK, 128, 0, stream>>>(XN, Wha, bha, Whr, bhr, Whi, bhi,
      out1, out2, out3, out4);
}

// Round 4
// 1631.608 us; speedup vs baseline: 1.6890x; 1.1077x over previous
//
#include <hip/hip_runtime.h>
#include <hip/hip_bf16.h>
#include <math.h>

// ---------------------------------------------------------------------------
// GPT decision-transformer forward on gfx950 — round 4.
// Round-4 changes: (1) GEMM K-loop is double-buffered (single barrier/step,
// async global_load_lds staged one tile ahead); (2) all GEMMs BN=64 with
// grids sized for >=2 blocks/CU (FC2/O: 528 blocks vs 264); (3) all-layer
// weight transpose at startup when ws_size allows (else per-layer fallback).
// ---------------------------------------------------------------------------

typedef __hip_bfloat16 bf16;
typedef __attribute__((ext_vector_type(4))) short s4v;
typedef __attribute__((ext_vector_type(8))) short s8v;
typedef __attribute__((ext_vector_type(4))) float f4v;
typedef unsigned int u32;

#define DEV static __device__ __forceinline__

constexpr int NBATCH = 2;
constexpr int NK   = 48;
constexpr int NNP  = 25;
constexpr int NC   = 768;
constexpr int NH   = 12;
constexpr int NL   = 6;
constexpr int NTOK = 29;
constexpr int NT   = NK * NTOK;    // 1392
constexpr int NM   = NBATCH * NT;  // 2784
constexpr int MPAD = 2816;         // 22 * 128

DEV float bs2f(short s) {
  unsigned u = ((unsigned)(unsigned short)s) << 16;
  float f; __builtin_memcpy(&f, &u, 4); return f;
}
DEV short f2bs(float f) {
  bf16 h = __float2bfloat16(f);
  short s; __builtin_memcpy(&s, &h, 2); return s;
}

// async global->LDS, 16 B/lane; LDS dest = wave-uniform base + lane*16
DEV void async16(const short* g, short* l) {
  __builtin_amdgcn_global_load_lds(
      (const __attribute__((address_space(1))) u32*)g,
      (__attribute__((address_space(3))) u32*)l, 16, 0, 0);
}

// ---------------------------------------------------------------------------
// Generic f32 (R,C) -> bf16 (C,R) transpose (for intW).
// ---------------------------------------------------------------------------
__global__ __launch_bounds__(256) void transpose_kernel(
    const float* __restrict__ src, bf16* __restrict__ dst, int R, int C)
{
  int c0 = blockIdx.x * 32, r0 = blockIdx.y * 32;
  __shared__ float tl[32][33];
  int rr = threadIdx.x >> 5, cc = threadIdx.x & 31;
#pragma unroll
  for (int p = 0; p < 4; p++)
    tl[rr + p * 8][cc] = src[(long)(r0 + rr + p * 8) * C + c0 + cc];
  __syncthreads();
#pragma unroll
  for (int p = 0; p < 4; p++)
    dst[(long)(c0 + rr + p * 8) * R + r0 + cc] = __float2bfloat16(tl[cc][rr + p * 8]);
}

// Per-layer (or all-layer) weight transpose+convert. grid = 6912 * nlayers.
// multi=1: dst gets per-layer offset; multi=0: dst offset 0 (per-layer reuse).
__global__ __launch_bounds__(256) void transpose_layer_kernel(
    const float* __restrict__ Wq, const float* __restrict__ Wk,
    const float* __restrict__ Wv, const float* __restrict__ Wo,
    const float* __restrict__ Wm1, const float* __restrict__ Wm2,
    bf16* __restrict__ WqkvT, bf16* __restrict__ WoT,
    bf16* __restrict__ Wm1T, bf16* __restrict__ Wm2T, int multi)
{
  int blk = blockIdx.x;
  int l = blk / 6912, t = blk - l * 6912;
  long so = (long)l * 768 * 768;
  long mo = (long)l * 768 * 3072;
  long dl = multi ? l : 0;
  const float* src; bf16* dst; int R, C, tile;
  if (t < 1728) {
    int m = t / 576; tile = t - m * 576;
    src = (m == 0 ? Wq : (m == 1 ? Wk : Wv)) + so;
    dst = WqkvT + dl * (2304L * 768) + (long)m * 768 * 768; R = 768; C = 768;
  } else if (t < 2304) { src = Wo + so;  dst = WoT  + dl * (768L * 768);  tile = t - 1728; R = 768;  C = 768;  }
  else if (t < 4608)   { src = Wm1 + mo; dst = Wm1T + dl * (3072L * 768); tile = t - 2304; R = 768;  C = 3072; }
  else                 { src = Wm2 + mo; dst = Wm2T + dl * (768L * 3072); tile = t - 4608; R = 3072; C = 768;  }
  int ct = C / 32;
  int tr = tile / ct, tc = tile - tr * ct;
  int r0 = tr * 32, c0 = tc * 32;
  __shared__ float tl[32][33];
  int rr = threadIdx.x >> 5, cc = threadIdx.x & 31;
#pragma unroll
  for (int p = 0; p < 4; p++)
    tl[rr + p * 8][cc] = src[(long)(r0 + rr + p * 8) * C + c0 + cc];
  __syncthreads();
#pragma unroll
  for (int p = 0; p < 4; p++)
    dst[(long)(c0 + rr + p * 8) * R + r0 + cc] = __float2bfloat16(tl[cc][rr + p * 8]);
}

// ---------------------------------------------------------------------------
// gather ie_in (96,1536) bf16 = [src_tab[i0] | dst_tab[i1]]
// ---------------------------------------------------------------------------
__global__ __launch_bounds__(256) void gather_ie_kernel(
    const int* __restrict__ intentions, const float* __restrict__ src_tab,
    const float* __restrict__ dst_tab, bf16* __restrict__ ie_in)
{
  int idx = blockIdx.x * 256 + threadIdx.x;
  if (idx >= 96 * 1536) return;
  int row = idx / 1536, col = idx - row * 1536;
  float v;
  if (col < 768) v = src_tab[intentions[row * 2 + 0] * 768 + col];
  else           v = dst_tab[intentions[row * 2 + 1] * 768 + col - 768];
  ie_in[idx] = __float2bfloat16(v);
}

// ---------------------------------------------------------------------------
// Embedding: X (B*T, C) f32. grid (96, 3); thread owns one channel c.
// ---------------------------------------------------------------------------
__global__ __launch_bounds__(256) void embed_kernel(
    const int* __restrict__ states, const int* __restrict__ actions,
    const float* __restrict__ rtgs, const int* __restrict__ timesteps,
    const float* __restrict__ pnp,
    const float* __restrict__ pos_emb, const float* __restrict__ gpe,
    const float* __restrict__ state_tab, const float* __restrict__ action_tab,
    const float* __restrict__ retW, const float* __restrict__ retb,
    const float* __restrict__ pnpW, const float* __restrict__ pnpb,
    const bf16* __restrict__ ieb, float* __restrict__ X)
{
  int bk = blockIdx.x;
  int b = bk / NK, ts = bk - b * NK;
  int c = blockIdx.y * 256 + threadIdx.x;

  float rtg = rtgs[bk];
  int tstep = timesteps[bk];
  int act   = actions[bk];

  long base = (long)(b * NT + ts * NTOK) * NC;
  float pos = gpe[(long)tstep * NC + c] + pos_emb[ts * NC + c];

  X[base + c] = rtg * retW[c] + retb[c] + pos;
  const int* sp = states + bk * NNP;
#pragma unroll
  for (int i = 0; i < NNP; i++)
    X[base + (1 + i) * NC + c] = state_tab[sp[i] * NC + c] + pos;
  X[base + 26 * NC + c] = action_tab[act * NC + c] + pos;
  float ap = pnpb[c];
  const float* pv = pnp + bk * NNP;
#pragma unroll
  for (int i = 0; i < NNP; i++) ap += pv[i] * pnpW[i * NC + c];
  X[base + 27 * NC + c] = ap + pos;
  X[base + 28 * NC + c] = __bfloat162float(ieb[bk * NC + c]) + pos;
}

// ---------------------------------------------------------------------------
// LayerNorm: X (f32) -> XN (bf16). One block per row.
// ---------------------------------------------------------------------------
__global__ __launch_bounds__(256) void ln_kernel(
    const float* __restrict__ X, bf16* __restrict__ XN,
    const float* __restrict__ g, const float* __restrict__ bt)
{
  int row = blockIdx.x, tid = threadIdx.x;
  const float* x = X + (long)row * NC;
  float v0 = x[tid], v1 = x[tid + 256], v2 = x[tid + 512];
  float s = v0 + v1 + v2;
#pragma unroll
  for (int o = 32; o > 0; o >>= 1) s += __shfl_down(s, o, 64);
  __shared__ float red[8];
  if ((tid & 63) == 0) red[tid >> 6] = s;
  __syncthreads();
  float mean = (red[0] + red[1] + red[2] + red[3]) * (1.0f / NC);
  float d0 = v0 - mean, d1 = v1 - mean, d2 = v2 - mean;
  float qq = d0 * d0 + d1 * d1 + d2 * d2;
#pragma unroll
  for (int o = 32; o > 0; o >>= 1) qq += __shfl_down(qq, o, 64);
  __syncthreads();
  if ((tid & 63) == 0) red[tid >> 6] = qq;
  __syncthreads();
  float var = (red[0] + red[1] + red[2] + red[3]) * (1.0f / NC);
  float rs = 1.0f / sqrtf(var + 1e-5f);
  bf16* xn = XN + (long)row * NC;
  xn[tid      ] = __float2bfloat16(d0 * rs * g[tid      ] + bt[tid      ]);
  xn[tid + 256] = __float2bfloat16(d1 * rs * g[tid + 256] + bt[tid + 256]);
  xn[tid + 512] = __float2bfloat16(d2 * rs * g[tid + 512] + bt[tid + 512]);
}

// ---------------------------------------------------------------------------
// Double-buffered MFMA GEMM. A (rows,K) bf16 rm; WT (N,K) bf16 rm. BN=64.
// BM in {128,64}. 256 thr, 4 waves; wave computes (BM/4)x64 via IM x 4
// 16x16x32 MFMA per K-step. Stage tile k+1 while computing tile k; ONE
// barrier per step (its vmcnt drain completes the prefetch).
// flags: bit0 GELU, bit1 resid += f32. Bias group select via Nsplit.
// ---------------------------------------------------------------------------
template<int BM>
__global__ __launch_bounds__(256) void gemm_kernel(
    const bf16* __restrict__ A, const bf16* __restrict__ WT,
    const float* __restrict__ b0, const float* __restrict__ b1,
    const float* __restrict__ b2, int Nsplit,
    bf16* __restrict__ outb, float* __restrict__ resid,
    int M, int N, int K, int flags)
{
  constexpr int IM  = BM / 64;   // MFMA row-subtiles per wave
  constexpr int ACH = BM / 64;   // A stage chunks per wave (16 rows each)
  __shared__ __align__(1024) short As[2][BM * 32];
  __shared__ __align__(1024) short Bs[2][64 * 32];

  int tid = threadIdx.x, wave = tid >> 6, lane = tid & 63;
  int quad = lane >> 4, l16 = lane & 15;
  int m0 = blockIdx.y * BM, n0 = blockIdx.x * 64;
  int wm = wave * (BM / 4);
  int lr = lane >> 2, lc = (lane & 3) * 8;

  const short* Ag = (const short*)A + (long)m0 * K + lc;
  const short* Bg = (const short*)WT + (long)n0 * K + lc;

  const short* ag[ACH]; int alo[ACH];
#pragma unroll
  for (int c = 0; c < ACH; c++) {
    int rbase = wave * (16 * ACH) + c * 16;
    ag[c] = Ag + (long)(rbase + lr) * K;
    alo[c] = rbase * 32;
  }
  const short* bg = Bg + (long)(wave * 16 + lr) * K;
  int blo = wave * 16 * 32;

  f4v zero4 = {0.f, 0.f, 0.f, 0.f};
  f4v acc[IM][4];
#pragma unroll
  for (int i = 0; i < IM; i++)
#pragma unroll
    for (int j = 0; j < 4; j++) acc[i][j] = zero4;

  int nk = K >> 5;
  // prologue: stage tile 0 -> buf 0
#pragma unroll
  for (int c = 0; c < ACH; c++) async16(ag[c], &As[0][alo[c]]);
  async16(bg, &Bs[0][blo]);
  __syncthreads();   // vmcnt(0) drain: tile 0 ready

  for (int kt = 0; kt < nk; kt++) {
    int cur = kt & 1, nxt = cur ^ 1;
    if (kt + 1 < nk) {
      int ko = (kt + 1) << 5;
#pragma unroll
      for (int c = 0; c < ACH; c++) async16(ag[c] + ko, &As[nxt][alo[c]]);
      async16(bg + ko, &Bs[nxt][blo]);
    }
    s8v af[IM], bf8[4];
#pragma unroll
    for (int i = 0; i < IM; i++) {
      const short* p = &As[cur][(wm + i * 16 + l16) * 32 + quad * 8];
      af[i].lo = *(const s4v*)p; af[i].hi = *(const s4v*)(p + 4);
    }
#pragma unroll
    for (int j = 0; j < 4; j++) {
      const short* p = &Bs[cur][(j * 16 + l16) * 32 + quad * 8];
      bf8[j].lo = *(const s4v*)p; bf8[j].hi = *(const s4v*)(p + 4);
    }
#pragma unroll
    for (int i = 0; i < IM; i++)
#pragma unroll
      for (int j = 0; j < 4; j++)
        acc[i][j] = __builtin_amdgcn_mfma_f32_16x16x32_bf16(af[i], bf8[j], acc[i][j], 0, 0, 0);
    __syncthreads();  // all reads of cur done; prefetch of nxt drained
  }

  // epilogue: C/D layout col=lane&15, row=quad*4+reg
#pragma unroll
  for (int i = 0; i < IM; i++) {
    int rbase = m0 + wm + i * 16 + quad * 4;
#pragma unroll
    for (int j = 0; j < 4; j++) {
      int bc = n0 + j * 16;
      int wsel = bc / Nsplit;
      const float* bp = wsel == 0 ? b0 : (wsel == 1 ? b1 : b2);
      float bv = bp[bc - wsel * Nsplit + l16];
      int col = bc + l16;
#pragma unroll
      for (int r = 0; r < 4; r++) {
        int row = rbase + r;
        if (row < M) {
          float v = acc[i][j][r] + bv;
          if (flags & 1) v = 0.5f * v * (1.0f + erff(v * 0.70710678118654752f));
          if (flags & 2) resid[(long)row * N + col] += v;
          else outb[(long)row * N + col] = __float2bfloat16(v);
        }
      }
    }
  }
}

// ---------------------------------------------------------------------------
// Flash-style causal attention. QKV packed (MPAD,2304). Output Yb bf16.
// ---------------------------------------------------------------------------
constexpr int ASTR = 72;

__global__ __launch_bounds__(256) void attn_kernel(
    const bf16* __restrict__ QKV, bf16* __restrict__ Yg)
{
  int qt = blockIdx.x, h = blockIdx.y, b = blockIdx.z;
  int q0 = qt * 64;
  int tid = threadIdx.x, wave = tid >> 6, lane = tid & 63, quad = lane >> 4, l16 = lane & 15;

  __shared__ short Qs[64 * ASTR];
  __shared__ short Ks[64 * ASTR];
  __shared__ short Vt[64 * ASTR];
  __shared__ short Ps[64 * ASTR];
  __shared__ float S[64 * 65];
  __shared__ float mrow[64], lrow[64], arow[64];
  __shared__ float red[256];

  if (tid < 64) { mrow[tid] = -1e30f; lrow[tid] = 0.f; }

  int r = tid >> 2, c16 = (tid & 3) * 16;
  const short* src = (const short*)QKV;
  s8v zz = {0,0,0,0,0,0,0,0};

  s8v qv0 = zz, qv1 = zz;
  if (q0 + r < NT) {
    const s8v* p = (const s8v*)(src + (long)(b * NT + q0 + r) * 2304 + h * 64 + c16);
    qv0 = p[0]; qv1 = p[1];
  }
  {
    short* qp = &Qs[r * ASTR + c16];
    *(s4v*)(qp    ) = qv0.lo; *(s4v*)(qp + 4) = qv0.hi;
    *(s4v*)(qp + 8) = qv1.lo; *(s4v*)(qp + 12) = qv1.hi;
  }

  f4v zero4 = {0.f, 0.f, 0.f, 0.f};
  f4v Of[4];
#pragma unroll
  for (int j = 0; j < 4; j++) Of[j] = zero4;

  int kend = q0 + 63; if (kend > NT - 1) kend = NT - 1;
  for (int k0 = 0; k0 <= kend; k0 += 64) {
    s8v kv0 = zz, kv1 = zz, vv0 = zz, vv1 = zz;
    if (k0 + r < NT) {
      const s8v* pk = (const s8v*)(src + (long)(b * NT + k0 + r) * 2304 + 768 + h * 64 + c16);
      kv0 = pk[0]; kv1 = pk[1];
      const s8v* pvv = (const s8v*)(src + (long)(b * NT + k0 + r) * 2304 + 1536 + h * 64 + c16);
      vv0 = pvv[0]; vv1 = pvv[1];
    }
    __syncthreads();
    {
      short* kp = &Ks[r * ASTR + c16];
      *(s4v*)(kp    ) = kv0.lo; *(s4v*)(kp + 4) = kv0.hi;
      *(s4v*)(kp + 8) = kv1.lo; *(s4v*)(kp + 12) = kv1.hi;
      short* vt = &Vt[c16 * ASTR + r];
      vt[ 0 * ASTR] = vv0.s0; vt[ 1 * ASTR] = vv0.s1; vt[ 2 * ASTR] = vv0.s2; vt[ 3 * ASTR] = vv0.s3;
      vt[ 4 * ASTR] = vv0.s4; vt[ 5 * ASTR] = vv0.s5; vt[ 6 * ASTR] = vv0.s6; vt[ 7 * ASTR] = vv0.s7;
      vt[ 8 * ASTR] = vv1.s0; vt[ 9 * ASTR] = vv1.s1; vt[10 * ASTR] = vv1.s2; vt[11 * ASTR] = vv1.s3;
      vt[12 * ASTR] = vv1.s4; vt[13 * ASTR] = vv1.s5; vt[14 * ASTR] = vv1.s6; vt[15 * ASTR] = vv1.s7;
    }
    __syncthreads();

    f4v sa[4];
#pragma unroll
    for (int j = 0; j < 4; j++) sa[j] = zero4;
#pragma unroll
    for (int ks = 0; ks < 2; ks++) {
      const short* pa = &Qs[(wave * 16 + l16) * ASTR + ks * 32 + quad * 8];
      s8v aq; aq.lo = *(const s4v*)pa; aq.hi = *(const s4v*)(pa + 4);
#pragma unroll
      for (int j = 0; j < 4; j++) {
        const short* pb = &Ks[(j * 16 + l16) * ASTR + ks * 32 + quad * 8];
        s8v bk8; bk8.lo = *(const s4v*)pb; bk8.hi = *(const s4v*)(pb + 4);
        sa[j] = __builtin_amdgcn_mfma_f32_16x16x32_bf16(aq, bk8, sa[j], 0, 0, 0);
      }
    }
#pragma unroll
    for (int j = 0; j < 4; j++) {
#pragma unroll
      for (int rg = 0; rg < 4; rg++) {
        int rloc = wave * 16 + quad * 4 + rg;
        int cloc = j * 16 + l16;
        int gq = q0 + rloc, gk = k0 + cloc;
        float sv = (gk <= gq && gq < NT) ? sa[j][rg] * 0.125f : -1e30f;
        S[rloc * 65 + cloc] = sv;
      }
    }
    __syncthreads();

    float mx = -1e30f;
#pragma unroll
    for (int c = 0; c < 16; c++) mx = fmaxf(mx, S[r * 65 + c16 + c]);
    red[r * 4 + (tid & 3)] = mx;
    __syncthreads();
    if (tid < 64) {
      float tm = fmaxf(fmaxf(red[tid * 4], red[tid * 4 + 1]), fmaxf(red[tid * 4 + 2], red[tid * 4 + 3]));
      float mn = fmaxf(mrow[tid], tm);
      arow[tid] = __expf(mrow[tid] - mn);
      mrow[tid] = mn;
    }
    __syncthreads();

    float mr = mrow[r];
    float psum = 0.f;
#pragma unroll
    for (int c = 0; c < 16; c++) {
      float e = __expf(S[r * 65 + c16 + c] - mr);
      psum += e;
      Ps[r * ASTR + c16 + c] = f2bs(e);
    }
    red[r * 4 + (tid & 3)] = psum;
    __syncthreads();
    if (tid < 64)
      lrow[tid] = lrow[tid] * arow[tid] + red[tid * 4] + red[tid * 4 + 1] + red[tid * 4 + 2] + red[tid * 4 + 3];
#pragma unroll
    for (int j = 0; j < 4; j++)
#pragma unroll
      for (int rg = 0; rg < 4; rg++)
        Of[j][rg] *= arow[wave * 16 + quad * 4 + rg];
    __syncthreads();

#pragma unroll
    for (int ks = 0; ks < 2; ks++) {
      const short* pa = &Ps[(wave * 16 + l16) * ASTR + ks * 32 + quad * 8];
      s8v ap8; ap8.lo = *(const s4v*)pa; ap8.hi = *(const s4v*)(pa + 4);
#pragma unroll
      for (int j = 0; j < 4; j++) {
        const short* pb = &Vt[(j * 16 + l16) * ASTR + ks * 32 + quad * 8];
        s8v vp8; vp8.lo = *(const s4v*)pb; vp8.hi = *(const s4v*)(pb + 4);
        Of[j] = __builtin_amdgcn_mfma_f32_16x16x32_bf16(ap8, vp8, Of[j], 0, 0, 0);
      }
    }
  }
  __syncthreads();
#pragma unroll
  for (int j = 0; j < 4; j++) {
#pragma unroll
    for (int rg = 0; rg < 4; rg++) {
      int rloc = wave * 16 + quad * 4 + rg;
      int gq = q0 + rloc;
      if (gq < NT) {
        float ov = Of[j][rg] / lrow[rloc];
        Yg[(long)(b * NT + gq) * NC + h * 64 + j * 16 + l16] = __float2bfloat16(ov);
      }
    }
  }
}

// ---------------------------------------------------------------------------
// Heads
// ---------------------------------------------------------------------------
__global__ __launch_bounds__(256) void head_logits_kernel(
    const bf16* __restrict__ XN, const float* __restrict__ Whs,
    const float* __restrict__ bhs, float* __restrict__ out)
{
  int idx = blockIdx.x * 256 + threadIdx.x;
  if (idx >= NM * 10) return;
  int row = idx / 10, n = idx - row * 10;
  const short* x = (const short*)XN + (long)row * NC;
  float a0 = bhs[n], a1 = 0.f, a2 = 0.f, a3 = 0.f;
  for (int k = 0; k < NC; k += 4) {
    a0 += bs2f(x[k    ]) * Whs[(k    ) * 10 + n];
    a1 += bs2f(x[k + 1]) * Whs[(k + 1) * 10 + n];
    a2 += bs2f(x[k + 2]) * Whs[(k + 2) * 10 + n];
    a3 += bs2f(x[k + 3]) * Whs[(k + 3) * 10 + n];
  }
  out[idx] = a0 + a1 + a2 + a3;
}

__global__ __launch_bounds__(128) void head_small_kernel(
    const bf16* __restrict__ XN,
    const float* __restrict__ Wha, const float* __restrict__ bha,
    const float* __restrict__ Whr, const float* __restrict__ bhr,
    const float* __restrict__ Whi, const float* __restrict__ bhi,
    float* __restrict__ outA, float* __restrict__ outR,
    float* __restrict__ outS, float* __restrict__ outD)
{
  int blk = blockIdx.x;
  int b = blk / NK, ts = blk - b * NK;
  int tid = threadIdx.x;
  if (tid >= 93) return;
  const short* xs = (const short*)XN;
  if (tid < 40) {
    long row = (long)(b * NT + ts * NTOK + 26) * NC;
    float a0 = bha[tid], a1 = 0.f, a2 = 0.f, a3 = 0.f;
    for (int k = 0; k < NC; k += 4) {
      a0 += bs2f(xs[row + k    ]) * Wha[(k    ) * 40 + tid];
      a1 += bs2f(xs[row + k + 1]) * Wha[(k + 1) * 40 + tid];
      a2 += bs2f(xs[row + k + 2]) * Wha[(k + 2) * 40 + tid];
      a3 += bs2f(xs[row + k + 3]) * Wha[(k + 3) * 40 + tid];
    }
    outA[blk * 40 + tid] = a0 + a1 + a2 + a3;
  } else if (tid == 40) {
    long row = (long)(b * NT + ts * NTOK) * NC;
    float a0 = bhr[0], a1 = 0.f, a2 = 0.f, a3 = 0.f;
    for (int k = 0; k < NC; k += 4) {
      a0 += bs2f(xs[row + k    ]) * Whr[k    ];
      a1 += bs2f(xs[row + k + 1]) * Whr[k + 1];
      a2 += bs2f(xs[row + k + 2]) * Whr[k + 2];
      a3 += bs2f(xs[row + k + 3]) * Whr[k + 3];
    }
    outR[blk] = a0 + a1 + a2 + a3;
  } else {
    int n = tid - 41;
    long row = (long)(b * NT + ts * NTOK + 28) * NC;
    float a0 = bhi[n], a1 = 0.f, a2 = 0.f, a3 = 0.f;
    for (int k = 0; k < NC; k += 4) {
      a0 += bs2f(xs[row + k    ]) * Whi[(k    ) * 52 + n];
      a1 += bs2f(xs[row + k + 1]) * Whi[(k + 1) * 52 + n];
      a2 += bs2f(xs[row + k + 2]) * Whi[(k + 2) * 52 + n];
      a3 += bs2f(xs[row + k + 3]) * Whi[(k + 3) * 52 + n];
    }
    if (n < 26) outS[blk * 26 + n] = a0 + a1 + a2 + a3;
    else        outD[blk * 26 + (n - 26)] = a0 + a1 + a2 + a3;
  }
}

// ---------------------------------------------------------------------------
extern "C" void kernel_launch(void* const* d_in, const int* in_sizes, int n_in,
                              void* d_out, int out_size, void* d_ws, size_t ws_size,
                              hipStream_t stream)
{
  (void)in_sizes; (void)n_in; (void)out_size;

  const int*   states     = (const int*)  d_in[0];
  const int*   actions    = (const int*)  d_in[1];
  const float* rtgs       = (const float*)d_in[2];
  const int*   timesteps  = (const int*)  d_in[3];
  const float* pnp        = (const float*)d_in[4];
  const int*   intentions = (const int*)  d_in[5];
  const float* pos_emb    = (const float*)d_in[6];
  const float* gpe        = (const float*)d_in[7];
  const float* state_tab  = (const float*)d_in[8];
  const float* action_tab = (const float*)d_in[9];
  const float* retW  = (const float*)d_in[10];
  const float* retb  = (const float*)d_in[11];
  const float* pnpW  = (const float*)d_in[12];
  const float* pnpb  = (const float*)d_in[13];
  const float* src_tab = (const float*)d_in[14];
  const float* dst_tab = (const float*)d_in[15];
  const float* intW  = (const float*)d_in[16];
  const float* intb  = (const float*)d_in[17];
  const float* ln1g  = (const float*)d_in[18];
  const float* ln1b  = (const float*)d_in[19];
  const float* ln2g  = (const float*)d_in[20];
  const float* ln2b  = (const float*)d_in[21];
  const float* Wq = (const float*)d_in[22];
  const float* bq = (const float*)d_in[23];
  const float* Wk = (const float*)d_in[24];
  const float* bk = (const float*)d_in[25];
  const float* Wv = (const float*)d_in[26];
  const float* bv = (const float*)d_in[27];
  const float* Wo = (const float*)d_in[28];
  const float* bo = (const float*)d_in[29];
  const float* Wm1 = (const float*)d_in[30];
  const float* bm1 = (const float*)d_in[31];
  const float* Wm2 = (const float*)d_in[32];
  const float* bm2 = (const float*)d_in[33];
  const float* lnfg = (const float*)d_in[34];
  const float* lnfb = (const float*)d_in[35];
  const float* Whs = (const float*)d_in[36];
  const float* bhs = (const float*)d_in[37];
  const float* Wha = (const float*)d_in[38];
  const float* bha = (const float*)d_in[39];
  const float* Whr = (const float*)d_in[40];
  const float* bhr = (const float*)d_in[41];
  const float* Whi = (const float*)d_in[42];
  const float* bhi = (const float*)d_in[43];

  // ws: [0, 30,277,632) activations: X f32 | XN bf16 | QKVb bf16 | Yb bf16
  // then weight region. big path: all-6-layer bf16 weights (84,934,656 B)
  // + int-embed scratch; fallback: single-layer weights (14,155,776 B) with
  // int-embed scratch overlapped (consumed before first layer transpose).
  char* wsb = (char*)d_ws;
  float* X   = (float*)(wsb);
  bf16* XN   = (bf16*)(wsb + 8650752);
  bf16* QKVb = (bf16*)(wsb + 12976128);
  bf16* Yb   = (bf16*)(wsb + 25952256);
  bf16* H1   = QKVb;                          // aliases QKVb|Yb
  bf16* WTbase = (bf16*)(wsb + 30277632);

  const size_t NEED_BIG = 30277632UL + 84934656UL + 2949120UL;  // 118,161,408
  bool big = ws_size >= NEED_BIG;

  long sQKV = 2304L * 768, sO = 768L * 768, sM1 = 3072L * 768, sM2 = 768L * 3072;
  bf16 *WqkvT, *WoT, *Wm1T, *Wm2T, *intWT;
  if (big) {
    WqkvT = WTbase;                 // 6 x sQKV
    WoT   = WqkvT + 6 * sQKV;       // 6 x sO
    Wm1T  = WoT   + 6 * sO;         // 6 x sM1
    Wm2T  = Wm1T  + 6 * sM1;        // 6 x sM2
    intWT = Wm2T  + 6 * sM2;
  } else {
    WqkvT = WTbase;
    WoT   = WqkvT + sQKV;
    Wm1T  = WoT + sO;
    Wm2T  = Wm1T + sM1;
    intWT = WTbase;                 // overlapped; consumed pre-transpose
  }
  bf16* ie_in = intWT + 768L * 1536;   // (128,1536)
  bf16* ieb   = ie_in + 128L * 1536;   // (128,768)

  float* out0 = (float*)d_out;
  float* out1 = out0 + 27840;
  float* out2 = out1 + 3840;
  float* out3 = out2 + 96;
  float* out4 = out3 + 2496;

  // --- embeddings ---
  transpose_kernel<<<dim3(24, 48), 256, 0, stream>>>(intW, intWT, 1536, 768);
  gather_ie_kernel<<<(96 * 1536 + 255) / 256, 256, 0, stream>>>(intentions, src_tab, dst_tab, ie_in);
  gemm_kernel<64><<<dim3(12, 2), 256, 0, stream>>>(ie_in, intWT, intb, intb, intb, 768,
      ieb, nullptr, 96, 768, 1536, 0);
  embed_kernel<<<dim3(96, 3), 256, 0, stream>>>(
      states, actions, rtgs, timesteps, pnp, pos_emb, gpe, state_tab, action_tab,
      retW, retb, pnpW, pnpb, ieb, X);

  if (big)
    transpose_layer_kernel<<<6912 * NL, 256, 0, stream>>>(
        Wq, Wk, Wv, Wo, Wm1, Wm2, WqkvT, WoT, Wm1T, Wm2T, 1);

  // --- transformer stack ---
  for (int l = 0; l < NL; l++) {
    const long wofs = (long)l * NC * NC;
    const long mofs = (long)l * NC * 4 * NC;
    if (!big)
      transpose_layer_kernel<<<6912, 256, 0, stream>>>(
          Wq + wofs, Wk + wofs, Wv + wofs, Wo + wofs, Wm1 + mofs, Wm2 + mofs,
          WqkvT, WoT, Wm1T, Wm2T, 0);
    bf16* wqkv = big ? WqkvT + l * sQKV : WqkvT;
    bf16* wo   = big ? WoT   + l * sO   : WoT;
    bf16* wm1  = big ? Wm1T  + l * sM1  : Wm1T;
    bf16* wm2  = big ? Wm2T  + l * sM2  : Wm2T;

    ln_kernel<<<NM, 256, 0, stream>>>(X, XN, ln1g + l * NC, ln1b + l * NC);
    gemm_kernel<128><<<dim3(36, 22), 256, 0, stream>>>(XN, wqkv,
        bq + l * NC, bk + l * NC, bv + l * NC, 768, QKVb, nullptr, NM, 2304, NC, 0);
    attn_kernel<<<dim3(22, NH, NBATCH), 256, 0, stream>>>(QKVb, Yb);
    gemm_kernel<64><<<dim3(12, 44), 256, 0, stream>>>(Yb, wo,
        bo + l * NC, bo + l * NC, bo + l * NC, 768, nullptr, X, NM, 768, NC, 2);
    ln_kernel<<<NM, 256, 0, stream>>>(X, XN, ln2g + l * NC, ln2b + l * NC);
    gemm_kernel<128><<<dim3(48, 22), 256, 0, stream>>>(XN, wm1,
        bm1 + l * 4 * NC, bm1 + l * 4 * NC, bm1 + l * 4 * NC, 4 * NC, H1, nullptr,
        NM, 3072, NC, 1);
    gemm_kernel<64><<<dim3(12, 44), 256, 0, stream>>>(H1, wm2,
        bm2 + l * NC, bm2 + l * NC, bm2 + l * NC, 768, nullptr, X, NM, 768, 4 * NC, 2);
  }
  ln_kernel<<<NM, 256, 0, stream>>>(X, XN, lnfg, lnfb);
  head_logits_kernel<<<(NM * 10 + 255) / 256, 256, 0, stream>>>(XN, Whs, bhs, out0);
  head_small_kernel<<<NBATCH * NK, 128, 0, stream>>>(XN, Wha, bha, Whr, bhr, Whi, bhi,
      out1, out2, out3, out4);
}